// Round 2
// baseline (231.479 us; speedup 1.0000x reference)
//
#include <hip/hip_runtime.h>
#include <hip/hip_bf16.h>

#define B_  8
#define C_  384
#define N_  1024
#define NH_ 12
#define HD_ 32
#define D3_ 1152   // 3*C

typedef __bf16 bf16x8 __attribute__((ext_vector_type(8)));
typedef float  f32x4  __attribute__((ext_vector_type(4)));

__device__ __forceinline__ float b2f(ushort u) {
    return __uint_as_float(((unsigned int)u) << 16);
}
__device__ __forceinline__ ushort f2b(float f) {
    unsigned int i = __float_as_uint(f);
    unsigned int r = i + 0x7fffu + ((i >> 16) & 1u);  // RNE
    return (ushort)(r >> 16);
}

// ---------------------------------------------------------------------------
// Kernel 1: QKV projection.  qkv[b][n][d] = sum_c W[d][c] * x[b][c][n] + bias[d]
// x, W, bias are fp32; qkv stored bf16 with layout [B, N, 1152] so per-head
// Q/K/V fragments are contiguous in dc.
// ---------------------------------------------------------------------------
__global__ __launch_bounds__(256) void qkv_gemm(
    const float* __restrict__ x, const float* __restrict__ q_w,
    const float* __restrict__ q_b, const float* __restrict__ kv_w,
    const float* __restrict__ kv_b, ushort* __restrict__ qkv)
{
    const int b = blockIdx.z;
    const int n0 = blockIdx.x * 64;
    const int d0 = blockIdx.y * 64;
    const float* W;  const float* bias;  int drow0;
    if (d0 < 384) { W = q_w;  bias = q_b;  drow0 = d0; }
    else          { W = kv_w; bias = kv_b; drow0 = d0 - 384; }

    __shared__ ushort As[64 * 40];  // [n][c] (transposed-from-x), pad 40
    __shared__ ushort Bs[64 * 40];  // [d][c]

    const int tid = threadIdx.x;
    const int lane = tid & 63, wave = tid >> 6;
    const int quad = lane >> 4, l16 = lane & 15;

    f32x4 acc[4] = {};

    const float* xb = x + (size_t)b * C_ * N_;  // x[b][c][n] fp32

    for (int c0 = 0; c0 < C_; c0 += 32) {
        // stage A (transpose + cvt): x[b][c0+cc][n0+nn..nn+7] -> As[nn+j][cc]
        {
            int cc = tid >> 3;          // 0..31
            int nn = (tid & 7) * 8;     // 0..56
            const float* px = xb + (size_t)(c0 + cc) * N_ + n0 + nn;
            float4 a0 = *(const float4*)px;
            float4 a1 = *(const float4*)(px + 4);
            As[(nn + 0) * 40 + cc] = f2b(a0.x);
            As[(nn + 1) * 40 + cc] = f2b(a0.y);
            As[(nn + 2) * 40 + cc] = f2b(a0.z);
            As[(nn + 3) * 40 + cc] = f2b(a0.w);
            As[(nn + 4) * 40 + cc] = f2b(a1.x);
            As[(nn + 5) * 40 + cc] = f2b(a1.y);
            As[(nn + 6) * 40 + cc] = f2b(a1.z);
            As[(nn + 7) * 40 + cc] = f2b(a1.w);
        }
        // stage B (cvt): W[drow0+dd][c0+cs..cs+7] -> Bs[dd][cs..]
        {
            int dd = tid >> 2;          // 0..63
            int cs = (tid & 3) * 8;     // 0,8,16,24
            const float* pw4 = W + (size_t)(drow0 + dd) * C_ + c0 + cs;
            float4 b0 = *(const float4*)pw4;
            float4 b1 = *(const float4*)(pw4 + 4);
            union { uint4 u; ushort s[8]; } cv;
            cv.s[0] = f2b(b0.x); cv.s[1] = f2b(b0.y);
            cv.s[2] = f2b(b0.z); cv.s[3] = f2b(b0.w);
            cv.s[4] = f2b(b1.x); cv.s[5] = f2b(b1.y);
            cv.s[6] = f2b(b1.z); cv.s[7] = f2b(b1.w);
            *(uint4*)&Bs[dd * 40 + cs] = cv.u;
        }
        __syncthreads();

        bf16x8 a = *(const bf16x8*)&As[(wave * 16 + l16) * 40 + quad * 8];
        #pragma unroll
        for (int t = 0; t < 4; ++t) {
            bf16x8 bb = *(const bf16x8*)&Bs[(t * 16 + l16) * 40 + quad * 8];
            acc[t] = __builtin_amdgcn_mfma_f32_16x16x32_bf16(a, bb, acc[t], 0, 0, 0);
        }
        __syncthreads();
    }

    // epilogue: D[row=n][col=d] ; row = quad*4+r (within wave strip), col = t*16+l16
    const size_t obase = (size_t)b * N_ * D3_;
    #pragma unroll
    for (int t = 0; t < 4; ++t) {
        float bv = bias[drow0 + t * 16 + l16];
        #pragma unroll
        for (int r = 0; r < 4; ++r) {
            int n = n0 + wave * 16 + quad * 4 + r;
            qkv[obase + (size_t)n * D3_ + d0 + t * 16 + l16] = f2b(acc[t][r] + bv);
        }
    }
}

// ---------------------------------------------------------------------------
// Kernel 2: bias table precompute. biasT[h][n][m] = bf16(rpb_table[rel_index[n][m]][h])
// ---------------------------------------------------------------------------
__global__ __launch_bounds__(256) void bias_gather(
    const int* __restrict__ rel, const float* __restrict__ tab,
    ushort* __restrict__ biasT)
{
    int i = blockIdx.x * 256 + threadIdx.x;  // over N*N
    int idx = rel[i];
    const float* row = tab + (size_t)idx * NH_;
    #pragma unroll
    for (int h = 0; h < NH_; ++h)
        biasT[(size_t)h * N_ * N_ + i] = f2b(row[h]);
}

// ---------------------------------------------------------------------------
// Kernel 3: attention. One WG = (b, h, 64 q-rows). Online softmax over m.
// All inputs/outputs are bf16 ws intermediates.
// ---------------------------------------------------------------------------
__global__ __launch_bounds__(256) void attn(
    const ushort* __restrict__ qkv, const ushort* __restrict__ biasT,
    ushort* __restrict__ O)
{
    const int b = blockIdx.z, h = blockIdx.y, n0 = blockIdx.x * 64;

    __shared__ ushort Ks[64 * 40];      // [m][dc]  pad 40
    __shared__ ushort Vs[32 * 72];      // [dc][m]  pad 72
    __shared__ ushort Ps[4 * 16 * 72];  // per-wave [16][72]

    const int tid = threadIdx.x;
    const int lane = tid & 63, wave = tid >> 6;
    const int quad = lane >> 4, l16 = lane & 15;
    const size_t bb = (size_t)b * N_ * D3_;

    // Q fragment (hd=32 == one MFMA K -> single frag, held all kernel)
    const int qrow = n0 + wave * 16 + l16;
    bf16x8 aq = *(const bf16x8*)(qkv + bb + (size_t)qrow * D3_ + h * HD_ + quad * 8);

    f32x4 oacc[2] = {};
    float mrow[4], lrow[4];
    #pragma unroll
    for (int r = 0; r < 4; ++r) { mrow[r] = -1e30f; lrow[r] = 0.0f; }

    const ushort* biash = biasT + (size_t)h * N_ * N_;
    const float C1 = 0.17677669529663687f * 1.4426950408889634f;  // scale*log2e
    const float C2 = 1.4426950408889634f;                          // log2e

    for (int m0 = 0; m0 < N_; m0 += 64) {
        // stage K: qkv[b][m0+mm][384+h*32+seg..] -> Ks[mm][seg..]
        {
            int mm = tid >> 2, seg = (tid & 3) * 8;
            *(uint4*)&Ks[mm * 40 + seg] =
                *(const uint4*)(qkv + bb + (size_t)(m0 + mm) * D3_ + 384 + h * HD_ + seg);
        }
        // stage V transposed: qkv[b][m0+mm][768+h*32+seg+j] -> Vs[seg+j][mm]
        {
            int mm = tid >> 2, seg = (tid & 3) * 8;
            uint4 t4 = *(const uint4*)(qkv + bb + (size_t)(m0 + mm) * D3_ + 768 + h * HD_ + seg);
            union { uint4 u; ushort s[8]; } cv; cv.u = t4;
            #pragma unroll
            for (int j = 0; j < 8; ++j) Vs[(seg + j) * 72 + mm] = cv.s[j];
        }
        __syncthreads();

        // S strip: 16 q-rows x 64 m
        f32x4 s[4];
        const f32x4 zero = {0.f, 0.f, 0.f, 0.f};
        #pragma unroll
        for (int t = 0; t < 4; ++t) {
            bf16x8 bk = *(const bf16x8*)&Ks[(t * 16 + l16) * 40 + quad * 8];
            s[t] = __builtin_amdgcn_mfma_f32_16x16x32_bf16(aq, bk, zero, 0, 0, 0);
        }

        // scale + bias, into log2 domain
        #pragma unroll
        for (int t = 0; t < 4; ++t) {
            int mcol = m0 + t * 16 + l16;
            #pragma unroll
            for (int r = 0; r < 4; ++r) {
                int q = n0 + wave * 16 + quad * 4 + r;
                float bv = b2f(biash[(size_t)q * N_ + mcol]);
                s[t][r] = s[t][r] * C1 + bv * C2;
            }
        }

        // online softmax (rows live across the 16 lanes of each quad)
        float newmax[4];
        #pragma unroll
        for (int r = 0; r < 4; ++r) {
            float mx = fmaxf(fmaxf(s[0][r], s[1][r]), fmaxf(s[2][r], s[3][r]));
            #pragma unroll
            for (int off = 1; off < 16; off <<= 1)
                mx = fmaxf(mx, __shfl_xor(mx, off, 64));
            newmax[r] = fmaxf(mrow[r], mx);
            float alpha = exp2f(mrow[r] - newmax[r]);
            mrow[r] = newmax[r];
            lrow[r] *= alpha;
            oacc[0][r] *= alpha;
            oacc[1][r] *= alpha;
        }
        float rsum[4] = {0.f, 0.f, 0.f, 0.f};
        #pragma unroll
        for (int t = 0; t < 4; ++t)
            #pragma unroll
            for (int r = 0; r < 4; ++r) {
                float p = exp2f(s[t][r] - newmax[r]);
                s[t][r] = p;
                rsum[r] += p;
            }
        #pragma unroll
        for (int r = 0; r < 4; ++r) {
            float sum = rsum[r];
            #pragma unroll
            for (int off = 1; off < 16; off <<= 1)
                sum += __shfl_xor(sum, off, 64);
            lrow[r] += sum;
        }

        // P: C-layout -> A-layout via per-wave LDS (no barrier: same-wave roundtrip)
        ushort* Pw = &Ps[wave * 16 * 72];
        #pragma unroll
        for (int t = 0; t < 4; ++t)
            #pragma unroll
            for (int r = 0; r < 4; ++r)
                Pw[(quad * 4 + r) * 72 + t * 16 + l16] = f2b(s[t][r]);

        #pragma unroll
        for (int kc = 0; kc < 2; ++kc) {
            bf16x8 ap = *(const bf16x8*)&Pw[l16 * 72 + kc * 32 + quad * 8];
            #pragma unroll
            for (int dt = 0; dt < 2; ++dt) {
                bf16x8 bv = *(const bf16x8*)&Vs[(dt * 16 + l16) * 72 + kc * 32 + quad * 8];
                oacc[dt] = __builtin_amdgcn_mfma_f32_16x16x32_bf16(ap, bv, oacc[dt], 0, 0, 0);
            }
        }
        __syncthreads();
    }

    // epilogue: O[b][q][h*32+dc]  (layout [B, N, C], contiguous in c), bf16
    #pragma unroll
    for (int dt = 0; dt < 2; ++dt)
        #pragma unroll
        for (int r = 0; r < 4; ++r) {
            int q = n0 + wave * 16 + quad * 4 + r;
            float outv = oacc[dt][r] / lrow[r];
            O[(size_t)b * N_ * C_ + (size_t)q * C_ + h * HD_ + dt * 16 + l16] = f2b(outv);
        }
}

// ---------------------------------------------------------------------------
// Kernel 4: output projection. out[b][d][n] = sum_c proj_w[d][c]*O[b][n][c] + proj_b[d]
// proj_w/proj_b fp32, O bf16, out fp32.
// ---------------------------------------------------------------------------
__global__ __launch_bounds__(256) void proj_gemm(
    const ushort* __restrict__ O, const float* __restrict__ pw,
    const float* __restrict__ pb, float* __restrict__ out)
{
    const int b = blockIdx.z;
    const int n0 = blockIdx.x * 64;
    const int d0 = blockIdx.y * 64;

    __shared__ ushort As[64 * 40];  // [d][c]
    __shared__ ushort Bs[64 * 40];  // [n][c]

    const int tid = threadIdx.x;
    const int lane = tid & 63, wave = tid >> 6;
    const int quad = lane >> 4, l16 = lane & 15;

    f32x4 acc[4] = {};
    const ushort* Ob = O + (size_t)b * N_ * C_;

    for (int c0 = 0; c0 < C_; c0 += 32) {
        int rr = tid >> 2, cs = (tid & 3) * 8;
        // A: proj_w fp32 -> bf16
        {
            const float* pw4 = pw + (size_t)(d0 + rr) * C_ + c0 + cs;
            float4 b0 = *(const float4*)pw4;
            float4 b1 = *(const float4*)(pw4 + 4);
            union { uint4 u; ushort s[8]; } cv;
            cv.s[0] = f2b(b0.x); cv.s[1] = f2b(b0.y);
            cv.s[2] = f2b(b0.z); cv.s[3] = f2b(b0.w);
            cv.s[4] = f2b(b1.x); cv.s[5] = f2b(b1.y);
            cv.s[6] = f2b(b1.z); cv.s[7] = f2b(b1.w);
            *(uint4*)&As[rr * 40 + cs] = cv.u;
        }
        // B: O bf16 direct copy
        *(uint4*)&Bs[rr * 40 + cs] = *(const uint4*)(Ob + (size_t)(n0 + rr) * C_ + c0 + cs);
        __syncthreads();

        bf16x8 a = *(const bf16x8*)&As[(wave * 16 + l16) * 40 + quad * 8];
        #pragma unroll
        for (int t = 0; t < 4; ++t) {
            bf16x8 bb = *(const bf16x8*)&Bs[(t * 16 + l16) * 40 + quad * 8];
            acc[t] = __builtin_amdgcn_mfma_f32_16x16x32_bf16(a, bb, acc[t], 0, 0, 0);
        }
        __syncthreads();
    }

    // D[row=d][col=n] -> out[b][d][n] (fp32), +proj_b[d]
    #pragma unroll
    for (int r = 0; r < 4; ++r) {
        int d = d0 + wave * 16 + quad * 4 + r;
        float bv = pb[d];
        #pragma unroll
        for (int t = 0; t < 4; ++t) {
            int n = n0 + t * 16 + l16;
            out[(size_t)b * C_ * N_ + (size_t)d * N_ + n] = acc[t][r] + bv;
        }
    }
}

// ---------------------------------------------------------------------------
extern "C" void kernel_launch(void* const* d_in, const int* in_sizes, int n_in,
                              void* d_out, int out_size, void* d_ws, size_t ws_size,
                              hipStream_t stream)
{
    const float* x      = (const float*)d_in[0];
    const float* q_w    = (const float*)d_in[1];
    const float* q_b    = (const float*)d_in[2];
    const float* kv_w   = (const float*)d_in[3];
    const float* kv_b   = (const float*)d_in[4];
    const float* proj_w = (const float*)d_in[5];
    const float* proj_b = (const float*)d_in[6];
    const float* rpb    = (const float*)d_in[7];
    const int*   rel    = (const int*)d_in[8];
    float* out = (float*)d_out;

    char* ws = (char*)d_ws;
    ushort* qkv   = (ushort*)ws;                                    // 8*1024*1152*2 = 18,874,368 B
    ushort* biasT = (ushort*)(ws + 18874368);                       // 12*1024*1024*2 = 25,165,824 B
    ushort* O     = (ushort*)(ws + 18874368 + 25165824);            // 8*1024*384*2  =  6,291,456 B

    qkv_gemm  <<<dim3(16, 18, B_), 256, 0, stream>>>(x, q_w, q_b, kv_w, kv_b, qkv);
    bias_gather<<<dim3((N_ * N_) / 256), 256, 0, stream>>>(rel, rpb, biasT);
    attn      <<<dim3(16, NH_, B_), 256, 0, stream>>>(qkv, biasT, O);
    proj_gemm <<<dim3(16, 6, B_), 256, 0, stream>>>(O, proj_w, proj_b, out);
}